// Round 3
// baseline (226.639 us; speedup 1.0000x reference)
//
#include <hip/hip_runtime.h>
#include <hip/hip_bf16.h>
#include <stdint.h>

#define DIM 128

typedef __attribute__((ext_vector_type(8))) short short8;
typedef __attribute__((ext_vector_type(4))) float f32x4;
typedef __attribute__((ext_vector_type(8))) unsigned short ushort8;

__device__ __forceinline__ float bf2f(unsigned short u) {
    unsigned int x = ((unsigned int)u) << 16;
    return __builtin_bit_cast(float, x);
}
__device__ __forceinline__ unsigned short f2bf(float f) {
    unsigned int x = __builtin_bit_cast(unsigned int, f);
    x += 0x7fffu + ((x >> 16) & 1u);
    return (unsigned short)(x >> 16);
}

// ---------------------------------------------------------------------------
// Kernel 0: weight prep.
//   W1bcT[256][128]: c<128: W1bcT[c][k]=W1[128+k][c]   (res_i -> P cols)
//                    c>=128:            W1[256+k][c-128] (res_j -> Q cols)
//   packA: W1a^T in exact edge-wave B-frag load order (16KB elems):
//     packA[((T*4+s)*64+l)*8+x] = W1[k][col], col=T*16+(l&15), k=s*32+(l>>4)*8+x
// ---------------------------------------------------------------------------
__global__ void prep_weights(const float* __restrict__ W1,
                             unsigned short* __restrict__ W1bcT,
                             unsigned short* __restrict__ packA) {
    int t = blockIdx.x * 256 + threadIdx.x;   // 0 .. 49151
    if (t < 256 * 128) {
        int c = t >> 7, k = t & 127;
        int row = 128 + ((c >> 7) << 7) + k;
        W1bcT[t] = f2bf(W1[row * DIM + (c & 127)]);
    } else {
        int o = t - 256 * 128;                // 0 .. 16383
        int x = o & 7, l = (o >> 3) & 63, o2 = o >> 9;  // o2: 0..31
        int s = o2 & 3, T = o2 >> 2;
        int col = T * 16 + (l & 15);
        int k = s * 32 + (l >> 4) * 8 + x;
        packA[o] = f2bf(W1[k * DIM + col]);
    }
}

// ---------------------------------------------------------------------------
// Kernel 1: per-node precompute (fused):
//   nf16[n] = bf16(nf[n]);  PQ[n][0:128]=res@W1b + b1,  [128:256]=res@W1c  (bf16)
// 64 nodes/block, 512 thr = 8 waves: wave tile 32 nodes x 64 cols.
// (verified structure from R1)
// ---------------------------------------------------------------------------
__global__ __launch_bounds__(512) void precompute_PQ(
    const float* __restrict__ nf, const float* __restrict__ centroid,
    const unsigned short* __restrict__ W1bcT, const float* __restrict__ b1,
    unsigned short* __restrict__ nf16, unsigned short* __restrict__ PQ, int npg)
{
    __shared__ char sA[64 * 256];  // bf16 [64 rows][128 k], swizzled
    const int t = threadIdx.x;
    const int n0 = blockIdx.x * 64;

    {   // stage residual -> bf16 LDS; also emit nf16
        int row = t >> 3;            // 64 rows, 8 threads each
        int c0 = (t & 7) * 16;
        int n = n0 + row;
        int g = n / npg;
        const f32x4* nv = (const f32x4*)(nf + (size_t)n * DIM + c0);
        const f32x4* cv = (const f32x4*)(centroid + (size_t)g * DIM + c0);
        unsigned short sh[16];
        ushort8 raw[2];
#pragma unroll
        for (int u = 0; u < 4; ++u) {
            f32x4 a = nv[u], c = cv[u];
#pragma unroll
            for (int x = 0; x < 4; ++x) {
                raw[u >> 1][(u & 1) * 4 + x] = f2bf(a[x]);
                sh[u * 4 + x] = f2bf(a[x] - c[x]);
            }
        }
        *(ushort8*)(nf16 + (size_t)n * DIM + c0)     = raw[0];
        *(ushort8*)(nf16 + (size_t)n * DIM + c0 + 8) = raw[1];
#pragma unroll
        for (int v = 0; v < 2; ++v) {
            int inrow = c0 * 2 + v * 16;
            int phys = row * 256 + (inrow ^ ((row & 7) << 4));
            *(short8*)(sA + phys) = *(const short8*)(sh + v * 8);
        }
    }

    const int wid = t >> 6, l = t & 63, lo = l & 15, hi = l >> 4;
    const int wm = wid & 1, wn = wid >> 1;  // wm: node-half(32), wn: col-quarter(64)

    short8 B[4][4];
#pragma unroll
    for (int nt = 0; nt < 4; ++nt) {
        int row = wn * 64 + nt * 16 + lo;
        const short8* wp = (const short8*)(W1bcT + (size_t)row * DIM + hi * 8);
#pragma unroll
        for (int kk = 0; kk < 4; ++kk) B[nt][kk] = wp[kk * 4];
    }

    __syncthreads();

    f32x4 acc[2][4];
#pragma unroll
    for (int mt = 0; mt < 2; ++mt)
#pragma unroll
        for (int nt = 0; nt < 4; ++nt) acc[mt][nt] = (f32x4)0.0f;

#pragma unroll
    for (int kk = 0; kk < 4; ++kk) {
        short8 a[2];
#pragma unroll
        for (int mt = 0; mt < 2; ++mt) {
            int row = wm * 32 + mt * 16 + lo;
            int inrow = kk * 64 + hi * 16;
            int phys = row * 256 + (inrow ^ ((row & 7) << 4));
            a[mt] = *(const short8*)(sA + phys);
        }
#pragma unroll
        for (int mt = 0; mt < 2; ++mt)
#pragma unroll
            for (int nt = 0; nt < 4; ++nt)
                acc[mt][nt] = __builtin_amdgcn_mfma_f32_16x16x32_bf16(
                    a[mt], B[nt][kk], acc[mt][nt], 0, 0, 0);
    }

    // epilogue: +b1 on cols<128 (fold bias into P half), store bf16
#pragma unroll
    for (int nt = 0; nt < 4; ++nt) {
        int col = wn * 64 + nt * 16 + lo;
        float bb = (col < DIM) ? b1[col] : 0.0f;
#pragma unroll
        for (int mt = 0; mt < 2; ++mt)
#pragma unroll
            for (int q = 0; q < 4; ++q) {
                int n = n0 + wm * 32 + mt * 16 + hi * 4 + q;
                PQ[(size_t)n * 256 + col] = f2bf(acc[mt][nt][q] + bb);
            }
    }
}

// ---------------------------------------------------------------------------
// Kernel 2: per-edge K=128 GEMM + per-node term add:
//   score = relu(|ni-nj| @ W1a + P[i] + Q[j]) @ W2 + b2
// 32 edges/tile, ITERS=4 tiles/block, 256 thr = 4 waves (32 edges x 32 cols each).
// W1a B-frags held in registers across all 4 tiles; S=P+Q in stride-132 fp32 LDS.
// ---------------------------------------------------------------------------
#define ITERS 4
__global__ __launch_bounds__(256, 6) void edge_kernel(
    const unsigned short* __restrict__ nf16, const int* __restrict__ idx,
    const unsigned short* __restrict__ PQ, const unsigned short* __restrict__ packA,
    const float* __restrict__ W2, const float* __restrict__ b2,
    float* __restrict__ out, int E, int nTiles)
{
    __shared__ char  sD[32 * 256];   // bf16 [32 edges][128 k], swizzled
    __shared__ float sS[32 * 132];   // fp32 S = P_i + Q_j, stride 132
    __shared__ float sR[4][32];
    const int t = threadIdx.x;
    const int l = t & 63, wn = t >> 6, lo = l & 15, hi = l >> 4;

    // B-fragments: loaded once, reused for all ITERS tiles
    short8 B[2][4];
    {
        const short8* bp = (const short8*)packA;
#pragma unroll
        for (int nt = 0; nt < 2; ++nt)
#pragma unroll
            for (int kk = 0; kk < 4; ++kk)
                B[nt][kk] = bp[((wn * 2 + nt) * 4 + kk) * 64 + l];
    }
    float w2v[2];
#pragma unroll
    for (int nt = 0; nt < 2; ++nt) w2v[nt] = W2[wn * 32 + nt * 16 + lo];
    const float b2v = b2[0];

    for (int it = 0; it < ITERS; ++it) {
        int tile = blockIdx.x * ITERS + it;
        if (tile >= nTiles) break;           // block-uniform
        int e0 = tile * 32;

        {   // staging: 8 threads/edge, 16 k-cols each
            int e = t >> 3, c0 = (t & 7) * 16;
            int ge = e0 + e;
            int jj = 0, ii = 0;
            if (ge < E) { jj = idx[ge]; ii = idx[E + ge]; }  // [0]=j, [1]=i
            const ushort8* pi = (const ushort8*)(nf16 + (size_t)ii * DIM + c0);
            const ushort8* pj = (const ushort8*)(nf16 + (size_t)jj * DIM + c0);
            const ushort8* Pp = (const ushort8*)(PQ + (size_t)ii * 256 + c0);
            const ushort8* Qp = (const ushort8*)(PQ + (size_t)jj * 256 + DIM + c0);
            ushort8 a0 = pi[0], a1 = pi[1], c0v = pj[0], c1v = pj[1];
            ushort8 P0 = Pp[0], P1 = Pp[1], Q0 = Qp[0], Q1 = Qp[1];
            unsigned short d[16];
            float s[16];
#pragma unroll
            for (int x = 0; x < 8; ++x) {
                d[x]     = f2bf(fabsf(bf2f(a0[x]) - bf2f(c0v[x])));
                d[8 + x] = f2bf(fabsf(bf2f(a1[x]) - bf2f(c1v[x])));
                s[x]     = bf2f(P0[x]) + bf2f(Q0[x]);
                s[8 + x] = bf2f(P1[x]) + bf2f(Q1[x]);
            }
            int rs = e * 256, sw = (e & 7) << 4, inb = c0 * 2;
            *(short8*)(sD + rs + ((inb     ) ^ sw)) = *(const short8*)d;
            *(short8*)(sD + rs + ((inb + 16) ^ sw)) = *(const short8*)(d + 8);
#pragma unroll
            for (int u = 0; u < 4; ++u)
                *(f32x4*)(sS + e * 132 + c0 + u * 4) = *(const f32x4*)(s + u * 4);
        }
        __syncthreads();

        f32x4 acc[2][2];
#pragma unroll
        for (int mt = 0; mt < 2; ++mt)
#pragma unroll
            for (int nt = 0; nt < 2; ++nt) acc[mt][nt] = (f32x4)0.0f;

#pragma unroll
        for (int kk = 0; kk < 4; ++kk) {
            short8 a[2];
#pragma unroll
            for (int mt = 0; mt < 2; ++mt) {
                int row = mt * 16 + lo;
                int inrow = kk * 64 + hi * 16;
                a[mt] = *(const short8*)(sD + row * 256 + (inrow ^ ((row & 7) << 4)));
            }
#pragma unroll
            for (int mt = 0; mt < 2; ++mt)
#pragma unroll
                for (int nt = 0; nt < 2; ++nt)
                    acc[mt][nt] = __builtin_amdgcn_mfma_f32_16x16x32_bf16(
                        a[mt], B[nt][kk], acc[mt][nt], 0, 0, 0);
        }

        // epilogue: h = relu(acc + S); partial = sum_cols h * W2[col]
#pragma unroll
        for (int mt = 0; mt < 2; ++mt)
#pragma unroll
            for (int q = 0; q < 4; ++q) {
                int el = mt * 16 + hi * 4 + q;
                float s = 0.0f;
#pragma unroll
                for (int nt = 0; nt < 2; ++nt) {
                    int col = wn * 32 + nt * 16 + lo;
                    float h = acc[mt][nt][q] + sS[el * 132 + col];
                    s += fmaxf(h, 0.0f) * w2v[nt];
                }
                s += __shfl_xor(s, 1);
                s += __shfl_xor(s, 2);
                s += __shfl_xor(s, 4);
                s += __shfl_xor(s, 8);
                if (lo == 0) sR[wn][el] = s;
            }
        __syncthreads();   // sS/sD reads + sR writes complete
        if (t < 32) {
            int ge = e0 + t;
            if (ge < E)
                out[ge] = sR[0][t] + sR[1][t] + sR[2][t] + sR[3][t] + b2v;
        }
        // next iter's staging (sD/sS) is safe: sR writes only occur after the
        // next sync; sR reads above finish before this thread stages.
    }
}

// ---------------------------------------------------------------------------
extern "C" void kernel_launch(void* const* d_in, const int* in_sizes, int n_in,
                              void* d_out, int out_size, void* d_ws, size_t ws_size,
                              hipStream_t stream) {
    const float* nf       = (const float*)d_in[0];
    const int*   idx      = (const int*)d_in[1];
    const float* centroid = (const float*)d_in[2];
    const float* W1       = (const float*)d_in[4];
    const float* b1       = (const float*)d_in[5];
    const float* W2       = (const float*)d_in[6];
    const float* b2       = (const float*)d_in[7];
    float* out = (float*)d_out;

    const int n_nodes = in_sizes[0] / DIM;
    const int E       = in_sizes[1] / 2;
    const int bs      = in_sizes[2] / DIM;
    const int npg     = n_nodes / bs;

    unsigned short* nf16  = (unsigned short*)d_ws;                  // [n][128] bf16
    unsigned short* PQ    = nf16 + (size_t)n_nodes * DIM;           // [n][256] bf16
    unsigned short* W1bcT = PQ + (size_t)n_nodes * 256;             // 32768
    unsigned short* packA = W1bcT + 256 * 128;                      // 16384

    prep_weights<<<192, 256, 0, stream>>>(W1, W1bcT, packA);
    precompute_PQ<<<n_nodes / 64, 512, 0, stream>>>(nf, centroid, W1bcT, b1,
                                                    nf16, PQ, npg);
    int nTiles = (E + 31) / 32;
    edge_kernel<<<(nTiles + ITERS - 1) / ITERS, 256, 0, stream>>>(
        nf16, idx, PQ, packA, W2, b2, out, E, nTiles);
}

// Round 4
// 185.805 us; speedup vs baseline: 1.2198x; 1.2198x over previous
//
#include <hip/hip_runtime.h>
#include <hip/hip_bf16.h>
#include <stdint.h>

#define DIM 128
#define ITERS 16

typedef __attribute__((ext_vector_type(8))) short short8;
typedef __attribute__((ext_vector_type(4))) float f32x4;
typedef __attribute__((ext_vector_type(8))) unsigned short ushort8;

__device__ __forceinline__ float bf2f(unsigned short u) {
    unsigned int x = ((unsigned int)u) << 16;
    return __builtin_bit_cast(float, x);
}
__device__ __forceinline__ unsigned short f2bf(float f) {
    unsigned int x = __builtin_bit_cast(unsigned int, f);
    x += 0x7fffu + ((x >> 16) & 1u);
    return (unsigned short)(x >> 16);
}

// ---------------------------------------------------------------------------
// Kernel 0: weight prep (unchanged from R3).
//   W1bcT[256][128]: c<128: W1bcT[c][k]=W1[128+k][c]; c>=128: W1[256+k][c-128]
//   packA: W1a^T in exact edge-wave B-frag load order.
// ---------------------------------------------------------------------------
__global__ void prep_weights(const float* __restrict__ W1,
                             unsigned short* __restrict__ W1bcT,
                             unsigned short* __restrict__ packA) {
    int t = blockIdx.x * 256 + threadIdx.x;   // 0 .. 49151
    if (t < 256 * 128) {
        int c = t >> 7, k = t & 127;
        int row = 128 + ((c >> 7) << 7) + k;
        W1bcT[t] = f2bf(W1[row * DIM + (c & 127)]);
    } else {
        int o = t - 256 * 128;                // 0 .. 16383
        int x = o & 7, l = (o >> 3) & 63, o2 = o >> 9;  // o2: 0..31
        int s = o2 & 3, T = o2 >> 2;
        int col = T * 16 + (l & 15);
        int k = s * 32 + (l >> 4) * 8 + x;
        packA[o] = f2bf(W1[k * DIM + col]);
    }
}

// ---------------------------------------------------------------------------
// Kernel 1: per-node precompute (unchanged from R3):
//   nf16[n] = bf16(nf[n]);  PQ[n][0:128]=res@W1b + b1, [128:256]=res@W1c
// ---------------------------------------------------------------------------
__global__ __launch_bounds__(512) void precompute_PQ(
    const float* __restrict__ nf, const float* __restrict__ centroid,
    const unsigned short* __restrict__ W1bcT, const float* __restrict__ b1,
    unsigned short* __restrict__ nf16, unsigned short* __restrict__ PQ, int npg)
{
    __shared__ char sA[64 * 256];  // bf16 [64 rows][128 k], swizzled
    const int t = threadIdx.x;
    const int n0 = blockIdx.x * 64;

    {   // stage residual -> bf16 LDS; also emit nf16
        int row = t >> 3;
        int c0 = (t & 7) * 16;
        int n = n0 + row;
        int g = n / npg;
        const f32x4* nv = (const f32x4*)(nf + (size_t)n * DIM + c0);
        const f32x4* cv = (const f32x4*)(centroid + (size_t)g * DIM + c0);
        unsigned short sh[16];
        ushort8 raw[2];
#pragma unroll
        for (int u = 0; u < 4; ++u) {
            f32x4 a = nv[u], c = cv[u];
#pragma unroll
            for (int x = 0; x < 4; ++x) {
                raw[u >> 1][(u & 1) * 4 + x] = f2bf(a[x]);
                sh[u * 4 + x] = f2bf(a[x] - c[x]);
            }
        }
        *(ushort8*)(nf16 + (size_t)n * DIM + c0)     = raw[0];
        *(ushort8*)(nf16 + (size_t)n * DIM + c0 + 8) = raw[1];
#pragma unroll
        for (int v = 0; v < 2; ++v) {
            int inrow = c0 * 2 + v * 16;
            int phys = row * 256 + (inrow ^ ((row & 7) << 4));
            *(short8*)(sA + phys) = *(const short8*)(sh + v * 8);
        }
    }

    const int wid = t >> 6, l = t & 63, lo = l & 15, hi = l >> 4;
    const int wm = wid & 1, wn = wid >> 1;

    short8 B[4][4];
#pragma unroll
    for (int nt = 0; nt < 4; ++nt) {
        int row = wn * 64 + nt * 16 + lo;
        const short8* wp = (const short8*)(W1bcT + (size_t)row * DIM + hi * 8);
#pragma unroll
        for (int kk = 0; kk < 4; ++kk) B[nt][kk] = wp[kk * 4];
    }

    __syncthreads();

    f32x4 acc[2][4];
#pragma unroll
    for (int mt = 0; mt < 2; ++mt)
#pragma unroll
        for (int nt = 0; nt < 4; ++nt) acc[mt][nt] = (f32x4)0.0f;

#pragma unroll
    for (int kk = 0; kk < 4; ++kk) {
        short8 a[2];
#pragma unroll
        for (int mt = 0; mt < 2; ++mt) {
            int row = wm * 32 + mt * 16 + lo;
            int inrow = kk * 64 + hi * 16;
            int phys = row * 256 + (inrow ^ ((row & 7) << 4));
            a[mt] = *(const short8*)(sA + phys);
        }
#pragma unroll
        for (int mt = 0; mt < 2; ++mt)
#pragma unroll
            for (int nt = 0; nt < 4; ++nt)
                acc[mt][nt] = __builtin_amdgcn_mfma_f32_16x16x32_bf16(
                    a[mt], B[nt][kk], acc[mt][nt], 0, 0, 0);
    }

#pragma unroll
    for (int nt = 0; nt < 4; ++nt) {
        int col = wn * 64 + nt * 16 + lo;
        float bb = (col < DIM) ? b1[col] : 0.0f;
#pragma unroll
        for (int mt = 0; mt < 2; ++mt)
#pragma unroll
            for (int q = 0; q < 4; ++q) {
                int n = n0 + wm * 32 + mt * 16 + hi * 4 + q;
                PQ[(size_t)n * 256 + col] = f2bf(acc[mt][nt][q] + bb);
            }
    }
}

// ---------------------------------------------------------------------------
// staging: convert payload regs -> swizzled bf16 sD + fp32 sS
// ---------------------------------------------------------------------------
__device__ __forceinline__ void stage_convert_write(
    char* sD, float* sS, int e, int c0,
    ushort8 a0, ushort8 a1, ushort8 b0, ushort8 b1,
    ushort8 P0, ushort8 P1, ushort8 Q0, ushort8 Q1)
{
    unsigned short d[16];
    float s[16];
#pragma unroll
    for (int x = 0; x < 8; ++x) {
        d[x]     = f2bf(fabsf(bf2f(a0[x]) - bf2f(b0[x])));
        d[8 + x] = f2bf(fabsf(bf2f(a1[x]) - bf2f(b1[x])));
        s[x]     = bf2f(P0[x]) + bf2f(Q0[x]);
        s[8 + x] = bf2f(P1[x]) + bf2f(Q1[x]);
    }
    int rs = e * 256, sw = (e & 7) << 4, inb = c0 * 2;
    *(short8*)(sD + rs + ((inb     ) ^ sw)) = *(const short8*)d;
    *(short8*)(sD + rs + ((inb + 16) ^ sw)) = *(const short8*)(d + 8);
#pragma unroll
    for (int u = 0; u < 4; ++u)
        *(f32x4*)(sS + e * 132 + c0 + u * 4) = *(const f32x4*)(s + u * 4);
}

// ---------------------------------------------------------------------------
// Kernel 2: pipelined per-edge kernel.
//   score = relu(|ni-nj| @ W1a + P[i] + Q[j]) @ W2 + b2
// 32 edges/tile, ITERS tiles/block, 256 thr = 4 waves (32 edges x 32 cols).
// B resident in regs; tile t+1's gathers in flight across tile t's compute;
// indices run two tiles ahead. 2 barriers/tile.
// ---------------------------------------------------------------------------
__global__ __launch_bounds__(256, 4) void edge_kernel(
    const unsigned short* __restrict__ nf16, const int* __restrict__ idx,
    const unsigned short* __restrict__ PQ, const unsigned short* __restrict__ packA,
    const float* __restrict__ W2, const float* __restrict__ b2,
    float* __restrict__ out, int E, int nTiles)
{
    __shared__ char  sD[32 * 256];   // bf16 [32 edges][128 k], swizzled
    __shared__ float sS[32 * 132];   // fp32 S = P_i + Q_j, stride 132
    __shared__ float sR[4][32];
    const int t = threadIdx.x;
    const int l = t & 63, wn = t >> 6, lo = l & 15, hi = l >> 4;
    const int es = t >> 3, c0 = (t & 7) * 16;   // staging role: 8 thr/edge

    // resident B-fragments + epilogue constants
    short8 B[2][4];
    {
        const short8* bp = (const short8*)packA;
#pragma unroll
        for (int nt = 0; nt < 2; ++nt)
#pragma unroll
            for (int kk = 0; kk < 4; ++kk)
                B[nt][kk] = bp[((wn * 2 + nt) * 4 + kk) * 64 + l];
    }
    float w2v[2];
    w2v[0] = W2[wn * 32 + lo];
    w2v[1] = W2[wn * 32 + 16 + lo];
    const float b2v = b2[0];

    const int tile0 = blockIdx.x * ITERS;
    const int nT = min(ITERS, nTiles - tile0);

    // ---- prologue: stage tile 0 (blocking), issue tile 1, idx for tile 2 ----
    {
        int ge = tile0 * 32 + es;
        int jj = idx[ge], ii = idx[E + ge];
        const ushort8* pi = (const ushort8*)(nf16 + (size_t)ii * DIM + c0);
        const ushort8* pj = (const ushort8*)(nf16 + (size_t)jj * DIM + c0);
        const ushort8* Pp = (const ushort8*)(PQ + (size_t)ii * 256 + c0);
        const ushort8* Qp = (const ushort8*)(PQ + (size_t)jj * 256 + DIM + c0);
        stage_convert_write(sD, sS, es, c0, pi[0], pi[1], pj[0], pj[1],
                            Pp[0], Pp[1], Qp[0], Qp[1]);
    }
    ushort8 pA0, pA1, pB0, pB1, pP0, pP1, pQ0, pQ1;  // payload (next tile)
    int ii_n, jj_n;                                   // idx (tile after next)
    {
        int t1 = min(tile0 + 1, nTiles - 1);
        int ge = t1 * 32 + es;
        int jj = idx[ge], ii = idx[E + ge];
        const ushort8* pi = (const ushort8*)(nf16 + (size_t)ii * DIM + c0);
        const ushort8* pj = (const ushort8*)(nf16 + (size_t)jj * DIM + c0);
        const ushort8* Pp = (const ushort8*)(PQ + (size_t)ii * 256 + c0);
        const ushort8* Qp = (const ushort8*)(PQ + (size_t)jj * 256 + DIM + c0);
        pA0 = pi[0]; pA1 = pi[1]; pB0 = pj[0]; pB1 = pj[1];
        pP0 = Pp[0]; pP1 = Pp[1]; pQ0 = Qp[0]; pQ1 = Qp[1];
        int t2 = min(tile0 + 2, nTiles - 1);
        int ge2 = t2 * 32 + es;
        jj_n = idx[ge2]; ii_n = idx[E + ge2];
    }
    __syncthreads();

    for (int tt = 0; tt < nT; ++tt) {
        // ---- compute(tt) ----
        f32x4 acc[2][2];
#pragma unroll
        for (int mt = 0; mt < 2; ++mt)
#pragma unroll
            for (int nt = 0; nt < 2; ++nt) acc[mt][nt] = (f32x4)0.0f;

#pragma unroll
        for (int kk = 0; kk < 4; ++kk) {
            short8 a[2];
#pragma unroll
            for (int mt = 0; mt < 2; ++mt) {
                int row = mt * 16 + lo;
                int inrow = kk * 64 + hi * 16;
                a[mt] = *(const short8*)(sD + row * 256 + (inrow ^ ((row & 7) << 4)));
            }
#pragma unroll
            for (int mt = 0; mt < 2; ++mt)
#pragma unroll
                for (int nt = 0; nt < 2; ++nt)
                    acc[mt][nt] = __builtin_amdgcn_mfma_f32_16x16x32_bf16(
                        a[mt], B[nt][kk], acc[mt][nt], 0, 0, 0);
        }

        // ---- epilogue: relu(acc + S) . W2, in-wave reduce over 16 col-lanes ----
#pragma unroll
        for (int mt = 0; mt < 2; ++mt)
#pragma unroll
            for (int q = 0; q < 4; ++q) {
                int el = mt * 16 + hi * 4 + q;
                float s = 0.0f;
#pragma unroll
                for (int nt = 0; nt < 2; ++nt) {
                    int col = wn * 32 + nt * 16 + lo;
                    float h = acc[mt][nt][q] + sS[el * 132 + col];
                    s += fmaxf(h, 0.0f) * w2v[nt];
                }
                s += __shfl_xor(s, 1);
                s += __shfl_xor(s, 2);
                s += __shfl_xor(s, 4);
                s += __shfl_xor(s, 8);
                if (lo == 0) sR[wn][el] = s;
            }
        __syncthreads();   // barrier A: sD/sS reads + sR writes complete

        {
            int ge = (tile0 + tt) * 32 + t;
            if (t < 32 && ge < E)
                out[ge] = sR[0][t] + sR[1][t] + sR[2][t] + sR[3][t] + b2v;
        }

        if (tt + 1 < nT) {
            // consume payload(tt+1) -> LDS (vmcnt wait lands here, latency
            // already covered by compute(tt))
            stage_convert_write(sD, sS, es, c0, pA0, pA1, pB0, pB1,
                                pP0, pP1, pQ0, pQ1);
            // issue gathers for tile tt+2 (idx already resident)
            {
                const ushort8* pi = (const ushort8*)(nf16 + (size_t)ii_n * DIM + c0);
                const ushort8* pj = (const ushort8*)(nf16 + (size_t)jj_n * DIM + c0);
                const ushort8* Pp = (const ushort8*)(PQ + (size_t)ii_n * 256 + c0);
                const ushort8* Qp = (const ushort8*)(PQ + (size_t)jj_n * 256 + DIM + c0);
                pA0 = pi[0]; pA1 = pi[1]; pB0 = pj[0]; pB1 = pj[1];
                pP0 = Pp[0]; pP1 = Pp[1]; pQ0 = Qp[0]; pQ1 = Qp[1];
            }
            // idx for tile tt+3 (one iteration of flight)
            {
                int t3 = min(tile0 + tt + 3, nTiles - 1);
                int ge3 = t3 * 32 + es;
                jj_n = idx[ge3]; ii_n = idx[E + ge3];
            }
        }
        __syncthreads();   // barrier B: sD/sS(tt+1) visible; sR reads done
    }
}

// ---------------------------------------------------------------------------
extern "C" void kernel_launch(void* const* d_in, const int* in_sizes, int n_in,
                              void* d_out, int out_size, void* d_ws, size_t ws_size,
                              hipStream_t stream) {
    const float* nf       = (const float*)d_in[0];
    const int*   idx      = (const int*)d_in[1];
    const float* centroid = (const float*)d_in[2];
    const float* W1       = (const float*)d_in[4];
    const float* b1       = (const float*)d_in[5];
    const float* W2       = (const float*)d_in[6];
    const float* b2       = (const float*)d_in[7];
    float* out = (float*)d_out;

    const int n_nodes = in_sizes[0] / DIM;
    const int E       = in_sizes[1] / 2;
    const int bs      = in_sizes[2] / DIM;
    const int npg     = n_nodes / bs;

    unsigned short* nf16  = (unsigned short*)d_ws;                  // [n][128] bf16
    unsigned short* PQ    = nf16 + (size_t)n_nodes * DIM;           // [n][256] bf16
    unsigned short* W1bcT = PQ + (size_t)n_nodes * 256;             // 32768
    unsigned short* packA = W1bcT + 256 * 128;                      // 16384

    prep_weights<<<192, 256, 0, stream>>>(W1, W1bcT, packA);
    precompute_PQ<<<n_nodes / 64, 512, 0, stream>>>(nf, centroid, W1bcT, b1,
                                                    nf16, PQ, npg);
    int nTiles = (E + 31) / 32;
    edge_kernel<<<(nTiles + ITERS - 1) / ITERS, 256, 0, stream>>>(
        nf16, idx, PQ, packA, W2, b2, out, E, nTiles);
}